// Round 2
// baseline (407.569 us; speedup 1.0000x reference)
//
#include <hip/hip_runtime.h>
#include <cstdint>
#include <cstddef>

// ---------------------------------------------------------------------------
// SelectiveScan2D (Mamba-style block), MI355X/gfx950.  Round 2.
//   1. cast_misc:      x -> f16; negA = -exp(A_log)
//   2. transpose_cast: W_in, W_dt, W_out -> f16 (N x K)
//   3. gemm_bt<f16>:   xz = x @ W_in + b_in            (4096 x 4096)
//   4. conv_silu:      x_in = silu(causal dwconv(xz[:, :2048]))
//   5. gemm_bt<fused>: y = scan_epilogue(x_in @ W_dt + b_dt)   (4096 x 2048)
//   6. gemm_bt<f32>:   out = y @ W_out + b_out         (4096 x 1024)
// GEMM: 128x128 tile, BK=32, DOUBLE-BUFFERED LDS with raw s_waitcnt vmcnt(4)
// + s_barrier (keeps next tile's global_load_lds in flight across barrier),
// XOR-swizzled staging (kills 8-way ds_read bank conflicts),
// v_mfma_f32_16x16x32_f16, fp32 accumulate.
// ---------------------------------------------------------------------------

typedef _Float16 half8 __attribute__((ext_vector_type(8)));
typedef float floatx4 __attribute__((ext_vector_type(4)));

typedef const char __attribute__((address_space(1)))* gbl_cptr;
typedef char __attribute__((address_space(3)))* lds_ptr;

__device__ __forceinline__ void async_copy16(const void* g, void* l) {
  __builtin_amdgcn_global_load_lds((gbl_cptr)g, (lds_ptr)l, 16, 0, 0);
}

// ---- GEMM: C[M,N] = A[M,K] @ Bt[N,K]^T + bias. M,N mult 128, K mult 32.
// FUSED: epilogue computes selective-scan pointwise (A doubles as xin).
template <bool HALF_OUT, bool FUSED>
__global__ __launch_bounds__(256) void gemm_bt(
    const _Float16* __restrict__ A, const _Float16* __restrict__ Bt,
    const float* __restrict__ bias, float* __restrict__ Cf,
    _Float16* __restrict__ Ch, int N, int K,
    const _Float16* __restrict__ xz, const float* __restrict__ negA,
    const float* __restrict__ Dv) {
  __shared__ _Float16 lA[2][128 * 32];
  __shared__ _Float16 lB[2][128 * 32];
  const int tid = threadIdx.x;
  const int rowBase = blockIdx.y * 128;
  const int colBase = blockIdx.x * 128;
  const int lane = tid & 63;
  const int wv = tid >> 6;
  const int wr = (wv >> 1) * 64;  // wave row offset in tile
  const int wc = (wv & 1) * 64;   // wave col offset in tile
  const int lr = lane & 15;
  const int lq = lane >> 4;

  floatx4 acc[4][4];
#pragma unroll
  for (int i = 0; i < 4; ++i)
#pragma unroll
    for (int j = 0; j < 4; ++j) acc[i][j] = (floatx4)0.0f;

  // staging: thread -> 16B granule; LDS dest = tid*16 bytes (lane-contiguous,
  // required by global_load_lds). XOR-swizzle applies to the GLOBAL column:
  // LDS granule (row,c) holds global chunk (row, c ^ ((row>>1)&3)).
  const int ra = tid >> 2;      // row 0..63 (and +64)
  const int c = tid & 3;
  const int csw = (c ^ ((ra >> 1) & 3)) * 8;  // swizzled f16 col offset
  const int ldst = ra * 32 + c * 8;           // == tid*8 f16 == tid*16 B
  const _Float16* gA = A + (size_t)(rowBase + ra) * K + csw;
  const _Float16* gB = Bt + (size_t)(colBase + ra) * K + csw;

#define STAGE(buf, k0)                                        \
  {                                                           \
    async_copy16(gA + (k0), &lA[buf][ldst]);                  \
    async_copy16(gA + (size_t)64 * K + (k0), &lA[buf][ldst + 64 * 32]); \
    async_copy16(gB + (k0), &lB[buf][ldst]);                  \
    async_copy16(gB + (size_t)64 * K + (k0), &lB[buf][ldst + 64 * 32]); \
  }

  const int nIter = K >> 5;
  STAGE(0, 0);
  // reader-side swizzle: for fragment row rr = {wr|wc}+i*16+lr, chunk lq,
  // data sits at chunk lq ^ ((rr>>1)&3) = lq ^ ((lr>>1)&3)  (bases mult 16).
  const int ko = ((lq ^ ((lr >> 1) & 3))) * 8;

  for (int it = 0; it < nIter; ++it) {
    const int cur = it & 1;
    if (it + 1 < nIter) {
      STAGE(cur ^ 1, (it + 1) << 5);
      // wait for current tile's 4 copies only; next tile's 4 stay in flight
      asm volatile("s_waitcnt vmcnt(4)\n\ts_barrier" ::: "memory");
    } else {
      asm volatile("s_waitcnt vmcnt(0)\n\ts_barrier" ::: "memory");
    }
    half8 af[4], bf[4];
#pragma unroll
    for (int i = 0; i < 4; ++i)
      af[i] = *(const half8*)&lA[cur][(wr + i * 16 + lr) * 32 + ko];
#pragma unroll
    for (int j = 0; j < 4; ++j)
      bf[j] = *(const half8*)&lB[cur][(wc + j * 16 + lr) * 32 + ko];
#pragma unroll
    for (int i = 0; i < 4; ++i)
#pragma unroll
      for (int j = 0; j < 4; ++j)
        acc[i][j] = __builtin_amdgcn_mfma_f32_16x16x32_f16(af[i], bf[j],
                                                           acc[i][j], 0, 0, 0);
    // own ds_reads returned (lgkmcnt 0) before any wave restages this buffer
    asm volatile("s_waitcnt lgkmcnt(0)\n\ts_barrier" ::: "memory");
  }
#undef STAGE

  if (FUSED) {
    // ---- fused selective-scan epilogue (GEMM2): acc holds dtraw - b_dt ----
    __syncthreads();
    float* nA = (float*)&lA[0][0];  // 128 cols x 16 states = 8KB
    {
      const floatx4* gna = (const floatx4*)(negA + (size_t)colBase * 16);
      floatx4* sna = (floatx4*)nA;
      sna[tid] = gna[tid];
      sna[tid + 256] = gna[tid + 256];
    }
    __syncthreads();
#pragma unroll
    for (int j = 0; j < 4; ++j) {
      const int cl = wc + j * 16 + lr;  // col within tile
      const int colg = colBase + cl;
      float a16[16];
#pragma unroll
      for (int q = 0; q < 4; ++q)
        ((floatx4*)a16)[q] = ((const floatx4*)(nA + cl * 16))[q];
      const float bv = bias[colg];
      const float dsk = Dv[colg];
#pragma unroll
      for (int i = 0; i < 4; ++i) {
        const int row0 = rowBase + wr + i * 16 + lq * 4;
#pragma unroll
        for (int r = 0; r < 4; ++r) {
          const int row = row0 + r;
          const float dtr = acc[i][j][r] + bv;
          const float dt = fmaxf(dtr, 0.f) + log1pf(__expf(-fabsf(dtr)));
          float S = 0.f;
#pragma unroll
          for (int n = 0; n < 16; ++n) S += __expf(dt * a16[n]);
          const float xin = (float)A[(size_t)row * K + colg];  // A == xin
          const float z = (float)xz[(size_t)row * 4096 + 2048 + colg];
          const float zs = z / (1.f + __expf(-z));
          Ch[(size_t)row * N + colg] = (_Float16)(xin * (S + dsk) * zs);
        }
      }
    }
  } else {
#pragma unroll
    for (int j = 0; j < 4; ++j) {
      const int colg = colBase + wc + j * 16 + lr;
      const float bv = bias[colg];
#pragma unroll
      for (int i = 0; i < 4; ++i) {
        const int row0 = rowBase + wr + i * 16 + lq * 4;
#pragma unroll
        for (int r = 0; r < 4; ++r) {
          const float v = acc[i][j][r] + bv;
          if (HALF_OUT)
            Ch[(size_t)(row0 + r) * N + colg] = (_Float16)v;
          else
            Cf[(size_t)(row0 + r) * N + colg] = v;
        }
      }
    }
  }
}

// ---- x -> f16 cast + negA = -exp(A_log) ----
__global__ __launch_bounds__(256) void cast_misc(
    const float* __restrict__ x, const float* __restrict__ A_log,
    _Float16* __restrict__ x_h, float* __restrict__ negA) {
  const int idx = blockIdx.x * 256 + threadIdx.x;
  const int NX = 4096 * 1024;
  if (idx < NX) {
    x_h[idx] = (_Float16)x[idx];
  } else {
    const int j = idx - NX;
    if (j < 2048 * 16) negA[j] = -__expf(A_log[j]);
  }
}

// ---- W (R x C, f32) -> Wt (C x R, f16) ----
__global__ __launch_bounds__(256) void transpose_cast(
    const float* __restrict__ in, _Float16* __restrict__ out, int R, int C) {
  __shared__ float t[32][33];
  const int bc = blockIdx.x * 32;
  const int br = blockIdx.y * 32;
  const int tx = threadIdx.x & 31;
  const int ty = threadIdx.x >> 5;
#pragma unroll
  for (int yy = ty; yy < 32; yy += 8)
    t[yy][tx] = in[(size_t)(br + yy) * C + bc + tx];
  __syncthreads();
#pragma unroll
  for (int yy = ty; yy < 32; yy += 8)
    out[(size_t)(bc + yy) * R + br + tx] = (_Float16)t[tx][yy];
}

// ---- causal depthwise conv(K=4) + silu over xz[:, :2048] ----
__global__ __launch_bounds__(256) void conv_silu(
    const _Float16* __restrict__ xz, const float* __restrict__ conv_w,
    const float* __restrict__ conv_b, _Float16* __restrict__ xin_h) {
  const int idx = blockIdx.x * 256 + threadIdx.x;  // over 4096*2048
  const int i = idx & 2047;
  const int ml = idx >> 11;  // b*L + l
  const int l = ml & 2047;
  float a = conv_b[i];
#pragma unroll
  for (int k = 0; k < 4; ++k) {
    const int ll = l + k - 3;
    if (ll >= 0)
      a += conv_w[i * 4 + k] * (float)xz[(size_t)(ml + k - 3) * 4096 + i];
  }
  const float s = a / (1.f + __expf(-a));
  xin_h[idx] = (_Float16)s;
}

extern "C" void kernel_launch(void* const* d_in, const int* in_sizes, int n_in,
                              void* d_out, int out_size, void* d_ws,
                              size_t ws_size, hipStream_t stream) {
  const float* x = (const float*)d_in[0];
  const float* W_in = (const float*)d_in[1];
  const float* b_in = (const float*)d_in[2];
  const float* conv_w = (const float*)d_in[3];
  const float* conv_b = (const float*)d_in[4];
  const float* A_log = (const float*)d_in[5];
  const float* Dv = (const float*)d_in[6];
  const float* W_dt = (const float*)d_in[7];
  const float* b_dt = (const float*)d_in[8];
  const float* W_out = (const float*)d_in[9];
  const float* b_out = (const float*)d_in[10];
  float* out = (float*)d_out;

  char* ws = (char*)d_ws;
  size_t off = 0;
  auto alloc = [&](size_t bytes) -> void* {
    void* p = ws + off;
    off += (bytes + 255) & ~(size_t)255;
    return p;
  };
  _Float16* x_h = (_Float16*)alloc((size_t)4096 * 1024 * 2);
  _Float16* Win_t = (_Float16*)alloc((size_t)4096 * 1024 * 2);
  _Float16* Wdt_t = (_Float16*)alloc((size_t)2048 * 2048 * 2);
  _Float16* Wout_t = (_Float16*)alloc((size_t)1024 * 2048 * 2);
  _Float16* xz_h = (_Float16*)alloc((size_t)4096 * 4096 * 2);
  _Float16* xin_h = (_Float16*)alloc((size_t)4096 * 2048 * 2);
  _Float16* y_h = (_Float16*)alloc((size_t)4096 * 2048 * 2);
  float* negA = (float*)alloc((size_t)2048 * 16 * 4);

  cast_misc<<<(4096 * 1024 + 32768 + 255) / 256, 256, 0, stream>>>(x, A_log,
                                                                   x_h, negA);
  transpose_cast<<<dim3(4096 / 32, 1024 / 32), 256, 0, stream>>>(W_in, Win_t,
                                                                 1024, 4096);
  transpose_cast<<<dim3(2048 / 32, 2048 / 32), 256, 0, stream>>>(W_dt, Wdt_t,
                                                                 2048, 2048);
  transpose_cast<<<dim3(1024 / 32, 2048 / 32), 256, 0, stream>>>(W_out, Wout_t,
                                                                 2048, 1024);
  // xz = x @ W_in + b_in
  gemm_bt<true, false><<<dim3(4096 / 128, 4096 / 128), 256, 0, stream>>>(
      x_h, Win_t, b_in, nullptr, xz_h, 4096, 1024, nullptr, nullptr, nullptr);
  conv_silu<<<(4096 * 2048) / 256, 256, 0, stream>>>(xz_h, conv_w, conv_b,
                                                     xin_h);
  // y = scan(x_in @ W_dt + b_dt)   (fused epilogue)
  gemm_bt<true, true><<<dim3(2048 / 128, 4096 / 128), 256, 0, stream>>>(
      xin_h, Wdt_t, b_dt, nullptr, y_h, 2048, 2048, xz_h, negA, Dv);
  // out = y @ W_out + b_out
  gemm_bt<false, false><<<dim3(1024 / 128, 4096 / 128), 256, 0, stream>>>(
      y_h, Wout_t, b_out, out, nullptr, 1024, 2048, nullptr, nullptr, nullptr);
}

// Round 3
// 375.632 us; speedup vs baseline: 1.0850x; 1.0850x over previous
//
#include <hip/hip_runtime.h>
#include <cstdint>
#include <cstddef>

// ---------------------------------------------------------------------------
// SelectiveScan2D (Mamba-style block), MI355X/gfx950.  Round 3.
//   1. cast_misc:      x -> f16; negA = -exp(A_log)
//   2. transpose_cast: W_in, W_dt, W_out -> f16 (N x K)
//   3. gemm_bt<128,128>: xz = x @ W_in + b_in          (4096 x 4096)
//   4. conv_silu:      x_in = silu(causal dwconv(xz[:, :2048]))
//   5. gemm_bt<128,64,fused>: y = scan(x_in @ W_dt + b_dt)  (4096 x 2048)
//   6. gemm_bt<64,64>: out = y @ W_out + b_out         (4096 x 1024)
// GEMM: single-buffered LDS, BK=32, __syncthreads (R1 structure — raw-asm
// vmcnt pipelining regressed in R2: compiler re-inserts vmcnt(0)).
// XOR-swizzled staging kills ds_read bank conflicts. Tiles sized so every
// GEMM has >=1024 blocks (4 blocks/CU) for cross-block latency hiding.
// ---------------------------------------------------------------------------

typedef _Float16 half8 __attribute__((ext_vector_type(8)));
typedef float floatx4 __attribute__((ext_vector_type(4)));

typedef const char __attribute__((address_space(1)))* gbl_cptr;
typedef char __attribute__((address_space(3)))* lds_ptr;

__device__ __forceinline__ void async_copy16(const void* g, void* l) {
  __builtin_amdgcn_global_load_lds((gbl_cptr)g, (lds_ptr)l, 16, 0, 0);
}

// ---- GEMM: C[M,N] = A[M,K] @ Bt[N,K]^T + bias. TM|TN in {64,128}, K mult 32.
// FUSED: epilogue computes selective-scan pointwise (A doubles as xin).
template <int TM, int TN, bool HALF_OUT, bool FUSED>
__global__ __launch_bounds__(256) void gemm_bt(
    const _Float16* __restrict__ A, const _Float16* __restrict__ Bt,
    const float* __restrict__ bias, float* __restrict__ Cf,
    _Float16* __restrict__ Ch, int N, int K,
    const _Float16* __restrict__ xz, const float* __restrict__ negA,
    const float* __restrict__ Dv) {
  __shared__ _Float16 lA[TM * 32];
  __shared__ _Float16 lB[TN * 32];
  const int tid = threadIdx.x;
  const int rowBase = blockIdx.y * TM;
  const int colBase = blockIdx.x * TN;
  const int lane = tid & 63;
  const int wv = tid >> 6;
  constexpr int WR = TM / 2, WC = TN / 2;  // per-wave tile (2x2 wave grid)
  constexpr int FI = WR / 16, FJ = WC / 16;
  const int wr = (wv >> 1) * WR;
  const int wc = (wv & 1) * WC;
  const int lr = lane & 15;
  const int lq = lane >> 4;

  floatx4 acc[FI][FJ];
#pragma unroll
  for (int i = 0; i < FI; ++i)
#pragma unroll
    for (int j = 0; j < FJ; ++j) acc[i][j] = (floatx4)0.0f;

  // staging: thread -> 16B granule; LDS dest lane-contiguous (global_load_lds
  // constraint). XOR-swizzle on the GLOBAL column: LDS granule (row,c) holds
  // global chunk (row, c ^ ((row>>1)&3)).
  const int ra = tid >> 2;  // 0..63 (t-th copy adds 64*t rows; swizzle same)
  const int c = tid & 3;
  const int csw = (c ^ ((ra >> 1) & 3)) * 8;  // swizzled f16 col offset
  const int ldst = ra * 32 + c * 8;           // == tid*16 bytes
  const _Float16* gA = A + (size_t)(rowBase + ra) * K + csw;
  const _Float16* gB = Bt + (size_t)(colBase + ra) * K + csw;
  // reader-side swizzle: fragment row rr = base+lr (base mult 32), chunk lq
  // sits at chunk lq ^ ((lr>>1)&3).
  const int ko = (lq ^ ((lr >> 1) & 3)) * 8;

  for (int k0 = 0; k0 < K; k0 += 32) {
#pragma unroll
    for (int t = 0; t < TM / 64; ++t)
      async_copy16(gA + (size_t)(64 * t) * K + k0, &lA[t * 64 * 32 + ldst]);
#pragma unroll
    for (int t = 0; t < TN / 64; ++t)
      async_copy16(gB + (size_t)(64 * t) * K + k0, &lB[t * 64 * 32 + ldst]);
    __syncthreads();

    half8 af[FI], bf[FJ];
#pragma unroll
    for (int i = 0; i < FI; ++i)
      af[i] = *(const half8*)&lA[(wr + i * 16 + lr) * 32 + ko];
#pragma unroll
    for (int j = 0; j < FJ; ++j)
      bf[j] = *(const half8*)&lB[(wc + j * 16 + lr) * 32 + ko];
#pragma unroll
    for (int i = 0; i < FI; ++i)
#pragma unroll
      for (int j = 0; j < FJ; ++j)
        acc[i][j] = __builtin_amdgcn_mfma_f32_16x16x32_f16(af[i], bf[j],
                                                           acc[i][j], 0, 0, 0);
    __syncthreads();
  }

  // C/D layout: col = lane&15, row = (lane>>4)*4 + reg  (m89-verified)
  if (FUSED) {
    // ---- fused selective-scan epilogue: acc holds dtraw - b_dt ----
    float* nA = (float*)&lA[0];  // TN cols x 16 states f32
    {
      const floatx4* gna = (const floatx4*)(negA + (size_t)colBase * 16);
      floatx4* sna = (floatx4*)nA;
#pragma unroll
      for (int t = 0; t < TN / 64; ++t) sna[tid + t * 256] = gna[tid + t * 256];
    }
    __syncthreads();
#pragma unroll
    for (int j = 0; j < FJ; ++j) {
      const int cl = wc + j * 16 + lr;
      const int colg = colBase + cl;
      float a16[16];
#pragma unroll
      for (int q = 0; q < 4; ++q)
        ((floatx4*)a16)[q] = ((const floatx4*)(nA + cl * 16))[q];
      const float bv = bias[colg];
      const float dsk = Dv[colg];
#pragma unroll
      for (int i = 0; i < FI; ++i) {
        const int row0 = rowBase + wr + i * 16 + lq * 4;
#pragma unroll
        for (int r = 0; r < 4; ++r) {
          const int row = row0 + r;
          const float dtr = acc[i][j][r] + bv;
          const float dt = fmaxf(dtr, 0.f) + log1pf(__expf(-fabsf(dtr)));
          float S = 0.f;
#pragma unroll
          for (int n = 0; n < 16; ++n) S += __expf(dt * a16[n]);
          const float xin = (float)A[(size_t)row * K + colg];  // A == xin
          const float z = (float)xz[(size_t)row * 4096 + 2048 + colg];
          const float zs = z / (1.f + __expf(-z));
          Ch[(size_t)row * N + colg] = (_Float16)(xin * (S + dsk) * zs);
        }
      }
    }
  } else {
#pragma unroll
    for (int j = 0; j < FJ; ++j) {
      const int colg = colBase + wc + j * 16 + lr;
      const float bv = bias[colg];
#pragma unroll
      for (int i = 0; i < FI; ++i) {
        const int row0 = rowBase + wr + i * 16 + lq * 4;
#pragma unroll
        for (int r = 0; r < 4; ++r) {
          const float v = acc[i][j][r] + bv;
          if (HALF_OUT)
            Ch[(size_t)(row0 + r) * N + colg] = (_Float16)v;
          else
            Cf[(size_t)(row0 + r) * N + colg] = v;
        }
      }
    }
  }
}

// ---- x -> f16 cast + negA = -exp(A_log) ----
__global__ __launch_bounds__(256) void cast_misc(
    const float* __restrict__ x, const float* __restrict__ A_log,
    _Float16* __restrict__ x_h, float* __restrict__ negA) {
  const int idx = blockIdx.x * 256 + threadIdx.x;
  const int NX = 4096 * 1024;
  if (idx < NX) {
    x_h[idx] = (_Float16)x[idx];
  } else {
    const int j = idx - NX;
    if (j < 2048 * 16) negA[j] = -__expf(A_log[j]);
  }
}

// ---- W (R x C, f32) -> Wt (C x R, f16) ----
__global__ __launch_bounds__(256) void transpose_cast(
    const float* __restrict__ in, _Float16* __restrict__ out, int R, int C) {
  __shared__ float t[32][33];
  const int bc = blockIdx.x * 32;
  const int br = blockIdx.y * 32;
  const int tx = threadIdx.x & 31;
  const int ty = threadIdx.x >> 5;
#pragma unroll
  for (int yy = ty; yy < 32; yy += 8)
    t[yy][tx] = in[(size_t)(br + yy) * C + bc + tx];
  __syncthreads();
#pragma unroll
  for (int yy = ty; yy < 32; yy += 8)
    out[(size_t)(bc + yy) * R + br + tx] = (_Float16)t[tx][yy];
}

// ---- causal depthwise conv(K=4) + silu over xz[:, :2048] ----
__global__ __launch_bounds__(256) void conv_silu(
    const _Float16* __restrict__ xz, const float* __restrict__ conv_w,
    const float* __restrict__ conv_b, _Float16* __restrict__ xin_h) {
  const int idx = blockIdx.x * 256 + threadIdx.x;  // over 4096*2048
  const int i = idx & 2047;
  const int ml = idx >> 11;  // b*L + l
  const int l = ml & 2047;
  float a = conv_b[i];
#pragma unroll
  for (int k = 0; k < 4; ++k) {
    const int ll = l + k - 3;
    if (ll >= 0)
      a += conv_w[i * 4 + k] * (float)xz[(size_t)(ml + k - 3) * 4096 + i];
  }
  const float s = a / (1.f + __expf(-a));
  xin_h[idx] = (_Float16)s;
}

extern "C" void kernel_launch(void* const* d_in, const int* in_sizes, int n_in,
                              void* d_out, int out_size, void* d_ws,
                              size_t ws_size, hipStream_t stream) {
  const float* x = (const float*)d_in[0];
  const float* W_in = (const float*)d_in[1];
  const float* b_in = (const float*)d_in[2];
  const float* conv_w = (const float*)d_in[3];
  const float* conv_b = (const float*)d_in[4];
  const float* A_log = (const float*)d_in[5];
  const float* Dv = (const float*)d_in[6];
  const float* W_dt = (const float*)d_in[7];
  const float* b_dt = (const float*)d_in[8];
  const float* W_out = (const float*)d_in[9];
  const float* b_out = (const float*)d_in[10];
  float* out = (float*)d_out;

  char* ws = (char*)d_ws;
  size_t off = 0;
  auto alloc = [&](size_t bytes) -> void* {
    void* p = ws + off;
    off += (bytes + 255) & ~(size_t)255;
    return p;
  };
  _Float16* x_h = (_Float16*)alloc((size_t)4096 * 1024 * 2);
  _Float16* Win_t = (_Float16*)alloc((size_t)4096 * 1024 * 2);
  _Float16* Wdt_t = (_Float16*)alloc((size_t)2048 * 2048 * 2);
  _Float16* Wout_t = (_Float16*)alloc((size_t)1024 * 2048 * 2);
  _Float16* xz_h = (_Float16*)alloc((size_t)4096 * 4096 * 2);
  _Float16* xin_h = (_Float16*)alloc((size_t)4096 * 2048 * 2);
  _Float16* y_h = (_Float16*)alloc((size_t)4096 * 2048 * 2);
  float* negA = (float*)alloc((size_t)2048 * 16 * 4);

  cast_misc<<<(4096 * 1024 + 32768 + 255) / 256, 256, 0, stream>>>(x, A_log,
                                                                   x_h, negA);
  transpose_cast<<<dim3(4096 / 32, 1024 / 32), 256, 0, stream>>>(W_in, Win_t,
                                                                 1024, 4096);
  transpose_cast<<<dim3(2048 / 32, 2048 / 32), 256, 0, stream>>>(W_dt, Wdt_t,
                                                                 2048, 2048);
  transpose_cast<<<dim3(1024 / 32, 2048 / 32), 256, 0, stream>>>(W_out, Wout_t,
                                                                 2048, 1024);
  // xz = x @ W_in + b_in   (128x128 tile: 32x32 = 1024 blocks)
  gemm_bt<128, 128, true, false><<<dim3(32, 32), 256, 0, stream>>>(
      x_h, Win_t, b_in, nullptr, xz_h, 4096, 1024, nullptr, nullptr, nullptr);
  conv_silu<<<(4096 * 2048) / 256, 256, 0, stream>>>(xz_h, conv_w, conv_b,
                                                     xin_h);
  // y = scan(x_in @ W_dt + b_dt)   (128x64 tile: 32x32 = 1024 blocks, fused)
  gemm_bt<128, 64, true, true><<<dim3(32, 32), 256, 0, stream>>>(
      xin_h, Wdt_t, b_dt, nullptr, y_h, 2048, 2048, xz_h, negA, Dv);
  // out = y @ W_out + b_out   (64x64 tile: 16x64 = 1024 blocks)
  gemm_bt<64, 64, false, false><<<dim3(16, 64), 256, 0, stream>>>(
      y_h, Wout_t, b_out, out, nullptr, 1024, 2048, nullptr, nullptr, nullptr);
}